// Round 5
// baseline (347.586 us; speedup 1.0000x reference)
//
#include <hip/hip_runtime.h>
#include <hip/hip_bf16.h>
#include <math.h>

// ---------------------------------------------------------------------------
// SLADGNN round 5: faster deterministic CSR (EPB=2048, wave-shfl scans),
// higher-ILP gather aggregation (4/8 edges in flight), MFMA bf16 GEMMs with
// dinv-prescaled rows. Zero global atomics anywhere.
// ---------------------------------------------------------------------------

typedef __attribute__((ext_vector_type(8))) short short8;
typedef __attribute__((ext_vector_type(4))) float f32x4;

#define BKT_SHIFT 5
#define BKT_NODES 32
#define EPB 2048        // edges per sort_local block (391 blocks)
#define LCAP 1024       // per-bucket CSR capacity (mean 512, +22 sigma)
#define PREPN 28672     // prep_w elements
#define PREPB 112       // prep_w blocks

__device__ __forceinline__ short f2bs(float x) {
    __hip_bfloat16 b = __float2bfloat16(x);
    return *reinterpret_cast<short*>(&b);
}
__device__ __forceinline__ float2 bpair(unsigned u) {
    float lo = __uint_as_float(u << 16);
    float hi = __uint_as_float(u & 0xffff0000u);
    return make_float2(lo, hi);
}
__device__ __forceinline__ unsigned packbf(float a, float b) {
    unsigned la = (unsigned)(unsigned short)f2bs(a);
    unsigned hb = (unsigned)(unsigned short)f2bs(b);
    return la | (hb << 16);
}

// Block-wide exclusive scan of arr[0..n) in LDS. 2 barriers per 256-chunk.
__device__ __forceinline__ void block_excl_scan(int* __restrict__ arr, int n, int t) {
    __shared__ int wsums[4];
    int lane = t & 63, wv = t >> 6;
    int carry = 0;
    for (int c0 = 0; c0 < n; c0 += 256) {
        int i = c0 + t;
        int v = (i < n) ? arr[i] : 0;
        int orig = v;
#pragma unroll
        for (int off = 1; off < 64; off <<= 1) {
            int u = __shfl_up(v, off, 64);
            if (lane >= off) v += u;
        }
        if (lane == 63) wsums[wv] = v;
        __syncthreads();
        int w0 = wsums[0], w1 = wsums[1], w2 = wsums[2], w3 = wsums[3];
        int woff = (wv > 0 ? w0 : 0) + (wv > 1 ? w1 : 0) + (wv > 2 ? w2 : 0);
        int tot = w0 + w1 + w2 + w3;
        __syncthreads();
        if (i < n) arr[i] = carry + woff + (v - orig);
        carry += tot;
    }
}

// --------------------- CSR build (deterministic, no global atomics) --------

// One block per EPB-chunk: LDS hist -> scan -> LDS scatter -> coalesced
// writes of bucket-sorted chunk + (len,start) tables. Extra blocks: prep_w.
__global__ __launch_bounds__(256) void sort_local_kernel(const int* __restrict__ ei, int E,
                                                         int NB, int B,
                                                         int* __restrict__ glens,
                                                         int* __restrict__ gstart,
                                                         int* __restrict__ edge_sorted,
                                                         const float* __restrict__ W1,
                                                         const float* __restrict__ W2,
                                                         const float* __restrict__ W3,
                                                         __hip_bfloat16* __restrict__ Wp1,
                                                         __hip_bfloat16* __restrict__ Wp2,
                                                         __hip_bfloat16* __restrict__ Wp3) {
    int t = threadIdx.x;
    if ((int)blockIdx.x >= B) {
        // folded weight prep (independent work)
        int i = ((int)blockIdx.x - B) * 256 + t;
        if (i < 16384) {                      // W1: 128x128
            int k = i >> 7, n = i & 127;
            Wp1[(((k >> 3) * 128) + n) * 8 + (k & 7)] = __float2bfloat16(W1[i]);
        } else if (i < 24576) {               // W2: 128x64
            int j = i - 16384;
            int k = j >> 6, n = j & 63;
            Wp2[(((k >> 3) * 64) + n) * 8 + (k & 7)] = __float2bfloat16(W2[j]);
        } else if (i < PREPN) {               // W3: 64x64
            int j = i - 24576;
            int k = j >> 6, n = j & 63;
            Wp3[(((k >> 3) * 64) + n) * 8 + (k & 7)] = __float2bfloat16(W3[j]);
        }
        return;
    }
    extern __shared__ int lds[];
    int* hist  = lds;                 // NB
    int* lbase = lds + NB;            // NB
    int* sortd = lds + 2 * NB;        // EPB
    int blk = blockIdx.x;
    int e0 = blk * EPB;
    int cnt = E - e0;
    if (cnt > EPB) cnt = EPB;

    for (int i = t; i < NB; i += 256) hist[i] = 0;
    __syncthreads();
    for (int i = t; i < cnt; i += 256) {
        int dst = ei[E + e0 + i];
        atomicAdd(&hist[dst >> BKT_SHIFT], 1);
    }
    __syncthreads();
    for (int i = t; i < NB; i += 256) lbase[i] = hist[i];
    __syncthreads();
    block_excl_scan(lbase, NB, t);
    __syncthreads();
    // tables (coalesced, blk-major) BEFORE scatter mutates lbase
    for (int i = t; i < NB; i += 256) {
        glens[(size_t)blk * NB + i] = hist[i];
        gstart[(size_t)blk * NB + i] = lbase[i];
    }
    __syncthreads();
    for (int i = t; i < cnt; i += 256) {
        int src = ei[e0 + i];
        int dst = ei[E + e0 + i];
        int pos = atomicAdd(&lbase[dst >> BKT_SHIFT], 1);
        sortd[pos] = (src << BKT_SHIFT) | (dst & (BKT_NODES - 1));
    }
    __syncthreads();
    for (int i = t; i < cnt; i += 256) edge_sorted[e0 + i] = sortd[i];
}

__global__ void btot_kernel(const int* __restrict__ glens, int NB, int B,
                            int* __restrict__ btot) {
    int i = blockIdx.x * 256 + threadIdx.x;
    if (i < NB) {
        int sum = 0;
        for (int blk = 0; blk < B; ++blk) sum += glens[(size_t)blk * NB + i];
        btot[i] = sum;
    }
}

// single block: load btot -> scan -> bbase
__global__ __launch_bounds__(256) void scan_nb_kernel(const int* __restrict__ btot, int NB,
                                                      int* __restrict__ bbase) {
    extern __shared__ int arr[];
    int t = threadIdx.x;
    for (int i = t; i < NB; i += 256) arr[i] = btot[i];
    __syncthreads();
    block_excl_scan(arr, NB, t);
    __syncthreads();
    for (int i = t; i < NB; i += 256) bbase[i] = arr[i];
}

// One block per bucket: gather runs, counting-sort by local node, write CSR
// segment + row_ptr + dinv.
__global__ __launch_bounds__(256) void csr_build_kernel(const int* __restrict__ edge_sorted,
                                                        const int* __restrict__ glens,
                                                        const int* __restrict__ gstart,
                                                        const int* __restrict__ bbase,
                                                        int NB, int B, int N, int E,
                                                        int* __restrict__ row_ptr,
                                                        float* __restrict__ dinv,
                                                        int* __restrict__ csr) {
    __shared__ int lruns[512];
    __shared__ int loffs[512];
    __shared__ int sdeg[BKT_NODES];
    __shared__ int scur[BKT_NODES];
    __shared__ int raw[LCAP];
    __shared__ int srt[LCAP];
    int b = blockIdx.x;
    int t = threadIdx.x;

    for (int i = t; i < 512; i += 256) {
        int v = (i < B) ? glens[(size_t)i * NB + b] : 0;
        lruns[i] = v;
        loffs[i] = v;
    }
    if (t < BKT_NODES) sdeg[t] = 0;
    __syncthreads();
    block_excl_scan(loffs, B, t);
    __syncthreads();
    int cnt = loffs[B - 1] + lruns[B - 1];
    if (cnt > LCAP) cnt = LCAP;

    // gather runs into LDS (bucket-grouped order), all threads
    for (int r = t; r < B; r += 256) {
        int len = lruns[r];
        if (len) {
            int off = loffs[r];
            int st = r * EPB + gstart[(size_t)r * NB + b];
            for (int k = 0; k < len; ++k) {
                int p = off + k;
                if (p < LCAP) raw[p] = edge_sorted[st + k];
            }
        }
    }
    __syncthreads();

    for (int i = t; i < cnt; i += 256) atomicAdd(&sdeg[raw[i] & (BKT_NODES - 1)], 1);
    __syncthreads();
    int base = bbase[b];
    if (t < BKT_NODES) {
        int ssum = 0;
        for (int i = 0; i < t; ++i) ssum += sdeg[i];
        scur[t] = ssum;
        int node = b * BKT_NODES + t;
        if (node < N) {
            row_ptr[node] = base + ssum;
            dinv[node] = rsqrtf((float)(sdeg[t] + 1));   // +1 self loop
        }
    }
    if (b == 0 && t == 0) row_ptr[N] = E;
    __syncthreads();
    for (int i = t; i < cnt; i += 256) {
        int p = raw[i];
        int pos = atomicAdd(&scur[p & (BKT_NODES - 1)], 1);
        srt[pos] = p >> BKT_SHIFT;
    }
    __syncthreads();
    for (int i = t; i < cnt; i += 256) csr[base + i] = srt[i];
}

// --------------------------- MFMA GEMM -------------------------------------
// C[r][:] = dinv[r] * (A[r][:] @ W)   stored bf16 (pre-scaled rows).

template <int DI, int DO, bool AF32>
__global__ __launch_bounds__(256) void mfma_gemm_kernel(const void* __restrict__ Av,
                                                        const __hip_bfloat16* __restrict__ Wp,
                                                        const float* __restrict__ dinv,
                                                        __hip_bfloat16* __restrict__ C, int N) {
    constexpr int NT = DO / 16;
    int t = threadIdx.x;
    int wave = t >> 6, lane = t & 63;
    int q = lane >> 4, l16 = lane & 15;
    int rbase = blockIdx.x * 64 + wave * 16;
    int row = rbase + l16;
    int rowc = row < N ? row : N - 1;

    f32x4 acc[NT];
#pragma unroll
    for (int i = 0; i < NT; ++i) acc[i] = (f32x4){0.f, 0.f, 0.f, 0.f};

#pragma unroll
    for (int kt = 0; kt < DI / 32; ++kt) {
        int k0 = kt * 32 + q * 8;
        short8 afrag;
        if (AF32) {
            const float* A = (const float*)Av;
            const float* ap = A + (size_t)rowc * DI + k0;
            float4 lo = *(const float4*)ap;
            float4 hi = *(const float4*)(ap + 4);
            afrag[0] = f2bs(lo.x); afrag[1] = f2bs(lo.y);
            afrag[2] = f2bs(lo.z); afrag[3] = f2bs(lo.w);
            afrag[4] = f2bs(hi.x); afrag[5] = f2bs(hi.y);
            afrag[6] = f2bs(hi.z); afrag[7] = f2bs(hi.w);
        } else {
            const __hip_bfloat16* A = (const __hip_bfloat16*)Av;
            afrag = *(const short8*)(A + (size_t)rowc * DI + k0);
        }
        const short8* wrow = (const short8*)(Wp + (size_t)(kt * 4 + q) * DO * 8);
#pragma unroll
        for (int tt = 0; tt < NT; ++tt) {
            short8 bfrag = wrow[tt * 16 + l16];
            acc[tt] = __builtin_amdgcn_mfma_f32_16x16x32_bf16(afrag, bfrag, acc[tt], 0, 0, 0);
        }
    }
    // C/D layout: col = lane&15, row = (lane>>4)*4 + reg
#pragma unroll
    for (int r = 0; r < 4; ++r) {
        int gr = rbase + q * 4 + r;
        if (gr < N) {
            float dv = dinv[gr];
#pragma unroll
            for (int tt = 0; tt < NT; ++tt)
                C[(size_t)gr * DO + tt * 16 + l16] = __float2bfloat16(acc[tt][r] * dv);
        }
    }
}

// --------------------------- aggregation -----------------------------------
// Rows pre-scaled by dinv[src]:  out = relu( dvi*(r_self + sum r_src) + b ).

// D=128: quarter-wave per edge (4 in flight), 16 lanes x uint4 = 256 B/row.
__global__ __launch_bounds__(256) void agg128_kernel(const uint4* __restrict__ tmp,
                                                     const float* __restrict__ bias,
                                                     const float* __restrict__ dinv,
                                                     const int* __restrict__ row_ptr,
                                                     const int* __restrict__ csr_src,
                                                     uint4* __restrict__ outp, int N) {
    int lane = threadIdx.x & 63;
    int q = lane >> 4, sub = lane & 15;
    int node = blockIdx.x * 4 + (threadIdx.x >> 6);
    if (node >= N) return;
    float dvi = dinv[node];
    float a0 = 0, a1 = 0, a2 = 0, a3 = 0, a4 = 0, a5 = 0, a6 = 0, a7 = 0;
    if (q == 0) {
        uint4 sv = tmp[(size_t)node * 16 + sub];
        float2 p0 = bpair(sv.x), p1 = bpair(sv.y), p2 = bpair(sv.z), p3 = bpair(sv.w);
        a0 = p0.x; a1 = p0.y; a2 = p1.x; a3 = p1.y;
        a4 = p2.x; a5 = p2.y; a6 = p3.x; a7 = p3.y;
    }
    int beg = row_ptr[node], end = row_ptr[node + 1];
    for (int j = beg; j < end; j += 64) {
        int m = end - j;
        if (m > 64) m = 64;
        int s = (lane < m) ? csr_src[j + lane] : 0;
        int iters = (m + 3) >> 2;
        for (int k = 0; k < iters; ++k) {
            int e = 4 * k + q;
            int ec = (e < m) ? e : 0;
            int sk = __shfl(s, ec, 64);
            uint4 v = tmp[(size_t)sk * 16 + sub];
            if (e < m) {
                float2 p0 = bpair(v.x), p1 = bpair(v.y), p2 = bpair(v.z), p3 = bpair(v.w);
                a0 += p0.x; a1 += p0.y; a2 += p1.x; a3 += p1.y;
                a4 += p2.x; a5 += p2.y; a6 += p3.x; a7 += p3.y;
            }
        }
    }
    a0 += __shfl_xor(a0, 16, 64); a1 += __shfl_xor(a1, 16, 64);
    a2 += __shfl_xor(a2, 16, 64); a3 += __shfl_xor(a3, 16, 64);
    a4 += __shfl_xor(a4, 16, 64); a5 += __shfl_xor(a5, 16, 64);
    a6 += __shfl_xor(a6, 16, 64); a7 += __shfl_xor(a7, 16, 64);
    a0 += __shfl_xor(a0, 32, 64); a1 += __shfl_xor(a1, 32, 64);
    a2 += __shfl_xor(a2, 32, 64); a3 += __shfl_xor(a3, 32, 64);
    a4 += __shfl_xor(a4, 32, 64); a5 += __shfl_xor(a5, 32, 64);
    a6 += __shfl_xor(a6, 32, 64); a7 += __shfl_xor(a7, 32, 64);
    if (q == 0) {
        float4 b0 = *(const float4*)&bias[sub * 8];
        float4 b1 = *(const float4*)&bias[sub * 8 + 4];
        uint4 o;
        o.x = packbf(fmaxf(dvi * a0 + b0.x, 0.f), fmaxf(dvi * a1 + b0.y, 0.f));
        o.y = packbf(fmaxf(dvi * a2 + b0.z, 0.f), fmaxf(dvi * a3 + b0.w, 0.f));
        o.z = packbf(fmaxf(dvi * a4 + b1.x, 0.f), fmaxf(dvi * a5 + b1.y, 0.f));
        o.w = packbf(fmaxf(dvi * a6 + b1.z, 0.f), fmaxf(dvi * a7 + b1.w, 0.f));
        outp[(size_t)node * 16 + sub] = o;
    }
}

// D=64: eighth-wave per edge (8 in flight), 8 lanes x uint4 = 128 B/row.
__global__ __launch_bounds__(256) void agg64_kernel(const uint4* __restrict__ tmp,
                                                    const float* __restrict__ bias,
                                                    const float* __restrict__ dinv,
                                                    const int* __restrict__ row_ptr,
                                                    const int* __restrict__ csr_src,
                                                    uint4* __restrict__ outp, int N) {
    int lane = threadIdx.x & 63;
    int o8 = lane >> 3, sub = lane & 7;
    int node = blockIdx.x * 4 + (threadIdx.x >> 6);
    if (node >= N) return;
    float dvi = dinv[node];
    float a0 = 0, a1 = 0, a2 = 0, a3 = 0, a4 = 0, a5 = 0, a6 = 0, a7 = 0;
    if (o8 == 0) {
        uint4 sv = tmp[(size_t)node * 8 + sub];
        float2 p0 = bpair(sv.x), p1 = bpair(sv.y), p2 = bpair(sv.z), p3 = bpair(sv.w);
        a0 = p0.x; a1 = p0.y; a2 = p1.x; a3 = p1.y;
        a4 = p2.x; a5 = p2.y; a6 = p3.x; a7 = p3.y;
    }
    int beg = row_ptr[node], end = row_ptr[node + 1];
    for (int j = beg; j < end; j += 64) {
        int m = end - j;
        if (m > 64) m = 64;
        int s = (lane < m) ? csr_src[j + lane] : 0;
        int iters = (m + 7) >> 3;
        for (int k = 0; k < iters; ++k) {
            int e = 8 * k + o8;
            int ec = (e < m) ? e : 0;
            int sk = __shfl(s, ec, 64);
            uint4 v = tmp[(size_t)sk * 8 + sub];
            if (e < m) {
                float2 p0 = bpair(v.x), p1 = bpair(v.y), p2 = bpair(v.z), p3 = bpair(v.w);
                a0 += p0.x; a1 += p0.y; a2 += p1.x; a3 += p1.y;
                a4 += p2.x; a5 += p2.y; a6 += p3.x; a7 += p3.y;
            }
        }
    }
    a0 += __shfl_xor(a0, 8, 64); a1 += __shfl_xor(a1, 8, 64);
    a2 += __shfl_xor(a2, 8, 64); a3 += __shfl_xor(a3, 8, 64);
    a4 += __shfl_xor(a4, 8, 64); a5 += __shfl_xor(a5, 8, 64);
    a6 += __shfl_xor(a6, 8, 64); a7 += __shfl_xor(a7, 8, 64);
    a0 += __shfl_xor(a0, 16, 64); a1 += __shfl_xor(a1, 16, 64);
    a2 += __shfl_xor(a2, 16, 64); a3 += __shfl_xor(a3, 16, 64);
    a4 += __shfl_xor(a4, 16, 64); a5 += __shfl_xor(a5, 16, 64);
    a6 += __shfl_xor(a6, 16, 64); a7 += __shfl_xor(a7, 16, 64);
    a0 += __shfl_xor(a0, 32, 64); a1 += __shfl_xor(a1, 32, 64);
    a2 += __shfl_xor(a2, 32, 64); a3 += __shfl_xor(a3, 32, 64);
    a4 += __shfl_xor(a4, 32, 64); a5 += __shfl_xor(a5, 32, 64);
    a6 += __shfl_xor(a6, 32, 64); a7 += __shfl_xor(a7, 32, 64);
    if (o8 == 0) {
        float4 b0 = *(const float4*)&bias[sub * 8];
        float4 b1 = *(const float4*)&bias[sub * 8 + 4];
        uint4 o;
        o.x = packbf(fmaxf(dvi * a0 + b0.x, 0.f), fmaxf(dvi * a1 + b0.y, 0.f));
        o.y = packbf(fmaxf(dvi * a2 + b0.z, 0.f), fmaxf(dvi * a3 + b0.w, 0.f));
        o.z = packbf(fmaxf(dvi * a4 + b1.x, 0.f), fmaxf(dvi * a5 + b1.y, 0.f));
        o.w = packbf(fmaxf(dvi * a6 + b1.z, 0.f), fmaxf(dvi * a7 + b1.w, 0.f));
        outp[(size_t)node * 8 + sub] = o;
    }
}

// --------------------------- head ------------------------------------------

__global__ __launch_bounds__(256) void head_kernel(const unsigned* __restrict__ h,
                                                   const float* __restrict__ protos,
                                                   const float* __restrict__ Wf0,
                                                   const float* __restrict__ bf0,
                                                   const float* __restrict__ Wf1,
                                                   const float* __restrict__ bf1,
                                                   const int* __restrict__ y,
                                                   float* __restrict__ out, int N) {
    __shared__ float Hl[64 * 65];
    __shared__ float Pl[16 * 65];
    __shared__ float hh[64];
    __shared__ float pp[16];
    __shared__ float sim[64 * 17];
    __shared__ float Wf0l[128];
    __shared__ float bf0l[8];
    __shared__ float Wf1l[8];
    __shared__ float bf1l;
    int t = threadIdx.x;
    int n0 = blockIdx.x * 64;

    for (int idx = t; idx < 64 * 32; idx += 256) {
        int r = idx >> 5, c = idx & 31;
        int g = n0 + r;
        unsigned u = (g < N) ? h[(size_t)g * 32 + c] : 0u;
        float2 v = bpair(u);
        Hl[r * 65 + 2 * c] = v.x;
        Hl[r * 65 + 2 * c + 1] = v.y;
    }
    for (int idx = t; idx < 16 * 64; idx += 256) {
        int r = idx >> 6, c = idx & 63;
        Pl[r * 65 + c] = protos[idx];
    }
    if (t < 128) Wf0l[t] = Wf0[t];
    if (t < 8) { bf0l[t] = bf0[t]; Wf1l[t] = Wf1[t]; }
    if (t == 0) bf1l = bf1[0];
    __syncthreads();

    if (t < 64) {
        float s = 0.0f;
        for (int k = 0; k < 64; ++k) { float v = Hl[t * 65 + k]; s += v * v; }
        hh[t] = s;
    } else if (t < 80) {
        int p = t - 64;
        float s = 0.0f;
        for (int k = 0; k < 64; ++k) { float v = Pl[p * 65 + k]; s += v * v; }
        pp[p] = s;
    }
    __syncthreads();

    {
        int node = t & 63;
        int p4 = (t >> 6) * 4;
        float d0 = 0, d1 = 0, d2 = 0, d3 = 0;
        for (int k = 0; k < 64; ++k) {
            float hv = Hl[node * 65 + k];
            d0 += hv * Pl[(p4 + 0) * 65 + k];
            d1 += hv * Pl[(p4 + 1) * 65 + k];
            d2 += hv * Pl[(p4 + 2) * 65 + k];
            d3 += hv * Pl[(p4 + 3) * 65 + k];
        }
        float hhv = hh[node];
        float dd[4] = {d0, d1, d2, d3};
#pragma unroll
        for (int j = 0; j < 4; ++j) {
            float q = hhv + pp[p4 + j] - 2.0f * dd[j];
            q = q > 0.0f ? q : 0.0f;
            sim[node * 17 + p4 + j] = logf((q + 1.0f) / (q + 1e-4f));
        }
    }
    __syncthreads();

    if (t < 64) {
        int g = n0 + t;
        if (g < N) {
            float zacc = bf1l;
#pragma unroll
            for (int o = 0; o < 8; ++o) {
                float s = bf0l[o];
#pragma unroll
                for (int i2 = 0; i2 < 16; ++i2) s += sim[t * 17 + i2] * Wf0l[i2 * 8 + o];
                float gz = 0.5f * s * (1.0f + erff(s * 0.70710678118654752f));
                zacc += gz * Wf1l[o];
            }
            out[g] = 1.0f / (1.0f + expf(-zacc));
        }
    } else if (t < 128) {
        int g = n0 + (t - 64);
        if (g < N) out[N + g] = (float)y[g];
    }
}

// ---------------------------------------------------------------------------

extern "C" void kernel_launch(void* const* d_in, const int* in_sizes, int n_in,
                              void* d_out, int out_size, void* d_ws, size_t ws_size,
                              hipStream_t stream) {
    const float* x   = (const float*)d_in[0];
    const int*   ei  = (const int*)d_in[1];
    const int*   y   = (const int*)d_in[2];
    const float* W1  = (const float*)d_in[3];
    const float* b1  = (const float*)d_in[4];
    const float* W2  = (const float*)d_in[5];
    const float* b2  = (const float*)d_in[6];
    const float* W3  = (const float*)d_in[7];
    const float* b3  = (const float*)d_in[8];
    const float* pr  = (const float*)d_in[9];
    const float* Wf0 = (const float*)d_in[10];
    const float* bf0 = (const float*)d_in[11];
    const float* Wf1 = (const float*)d_in[12];
    const float* bf1 = (const float*)d_in[13];
    float* outp = (float*)d_out;

    const int N = in_sizes[2];       // 50000
    const int E = in_sizes[1] / 2;   // 800000
    const int NB = (N + BKT_NODES - 1) / BKT_NODES;   // 1563
    const int B = (E + EPB - 1) / EPB;                // 391 (<=512)

    char* w = (char*)d_ws;
    auto carve = [&](size_t bytes) {
        char* p = w;
        w += (bytes + 511) & ~(size_t)511;
        return p;
    };
    int*   glens   = (int*)carve((size_t)B * NB * 4);
    int*   gstart  = (int*)carve((size_t)B * NB * 4);
    int*   btot    = (int*)carve((size_t)NB * 4);
    int*   bbase   = (int*)carve((size_t)NB * 4);
    int*   esort   = (int*)carve((size_t)B * EPB * 4);
    int*   row_ptr = (int*)carve((size_t)(N + 1) * 4);
    float* dinv    = (float*)carve((size_t)N * 4);
    int*   csr     = (int*)carve((size_t)E * 4);
    __hip_bfloat16* Wp1 = (__hip_bfloat16*)carve(16384 * 2);
    __hip_bfloat16* Wp2 = (__hip_bfloat16*)carve(8192 * 2);
    __hip_bfloat16* Wp3 = (__hip_bfloat16*)carve(4096 * 2);
    __hip_bfloat16* bufT = (__hip_bfloat16*)carve((size_t)N * 128 * 2);
    __hip_bfloat16* bufH = (__hip_bfloat16*)carve((size_t)N * 128 * 2);

    size_t sort_lds = (size_t)(2 * NB + EPB) * 4;   // ~20.7 KB
    size_t scan_lds = (size_t)NB * 4;               // ~6.3 KB

    sort_local_kernel<<<B + PREPB, 256, sort_lds, stream>>>(ei, E, NB, B, glens, gstart, esort,
                                                            W1, W2, W3, Wp1, Wp2, Wp3);
    btot_kernel<<<(NB + 255) / 256, 256, 0, stream>>>(glens, NB, B, btot);
    scan_nb_kernel<<<1, 256, scan_lds, stream>>>(btot, NB, bbase);
    csr_build_kernel<<<NB, 256, 0, stream>>>(esort, glens, gstart, bbase, NB, B, N, E,
                                             row_ptr, dinv, csr);

    // L1: x(f32,128) @ W1 -> bufT(bf16,128, dinv-prescaled); agg128 -> bufH
    mfma_gemm_kernel<128, 128, true><<<(N + 63) / 64, 256, 0, stream>>>(x, Wp1, dinv, bufT, N);
    agg128_kernel<<<(N + 3) / 4, 256, 0, stream>>>((const uint4*)bufT, b1, dinv, row_ptr, csr,
                                                   (uint4*)bufH, N);
    // L2
    mfma_gemm_kernel<128, 64, false><<<(N + 63) / 64, 256, 0, stream>>>(bufH, Wp2, dinv, bufT, N);
    agg64_kernel<<<(N + 3) / 4, 256, 0, stream>>>((const uint4*)bufT, b2, dinv, row_ptr, csr,
                                                  (uint4*)bufH, N);
    // L3
    mfma_gemm_kernel<64, 64, false><<<(N + 63) / 64, 256, 0, stream>>>(bufH, Wp3, dinv, bufT, N);
    agg64_kernel<<<(N + 3) / 4, 256, 0, stream>>>((const uint4*)bufT, b3, dinv, row_ptr, csr,
                                                  (uint4*)bufH, N);
    // Head
    head_kernel<<<(N + 63) / 64, 256, 0, stream>>>((const unsigned*)bufH, pr, Wf0, bf0, Wf1, bf1,
                                                   y, outp, N);
}

// Round 6
// 259.100 us; speedup vs baseline: 1.3415x; 1.3415x over previous
//
#include <hip/hip_runtime.h>
#include <hip/hip_bf16.h>
#include <math.h>

// ---------------------------------------------------------------------------
// SLADGNN round 6: round-5 structure + fixed btot (block-per-bucket parallel
// reduction instead of 1563-thread serial loop; was 94us @ 0.26% occupancy).
// ---------------------------------------------------------------------------

typedef __attribute__((ext_vector_type(8))) short short8;
typedef __attribute__((ext_vector_type(4))) float f32x4;

#define BKT_SHIFT 5
#define BKT_NODES 32
#define EPB 2048        // edges per sort_local block (391 blocks)
#define LCAP 1024       // per-bucket CSR capacity (mean 512, +22 sigma)
#define PREPN 28672     // prep_w elements
#define PREPB 112       // prep_w blocks

__device__ __forceinline__ short f2bs(float x) {
    __hip_bfloat16 b = __float2bfloat16(x);
    return *reinterpret_cast<short*>(&b);
}
__device__ __forceinline__ float2 bpair(unsigned u) {
    float lo = __uint_as_float(u << 16);
    float hi = __uint_as_float(u & 0xffff0000u);
    return make_float2(lo, hi);
}
__device__ __forceinline__ unsigned packbf(float a, float b) {
    unsigned la = (unsigned)(unsigned short)f2bs(a);
    unsigned hb = (unsigned)(unsigned short)f2bs(b);
    return la | (hb << 16);
}

// Block-wide exclusive scan of arr[0..n) in LDS. 2 barriers per 256-chunk.
__device__ __forceinline__ void block_excl_scan(int* __restrict__ arr, int n, int t) {
    __shared__ int wsums[4];
    int lane = t & 63, wv = t >> 6;
    int carry = 0;
    for (int c0 = 0; c0 < n; c0 += 256) {
        int i = c0 + t;
        int v = (i < n) ? arr[i] : 0;
        int orig = v;
#pragma unroll
        for (int off = 1; off < 64; off <<= 1) {
            int u = __shfl_up(v, off, 64);
            if (lane >= off) v += u;
        }
        if (lane == 63) wsums[wv] = v;
        __syncthreads();
        int w0 = wsums[0], w1 = wsums[1], w2 = wsums[2], w3 = wsums[3];
        int woff = (wv > 0 ? w0 : 0) + (wv > 1 ? w1 : 0) + (wv > 2 ? w2 : 0);
        int tot = w0 + w1 + w2 + w3;
        __syncthreads();
        if (i < n) arr[i] = carry + woff + (v - orig);
        carry += tot;
    }
}

// --------------------- CSR build (deterministic, no global atomics) --------

__global__ __launch_bounds__(256) void sort_local_kernel(const int* __restrict__ ei, int E,
                                                         int NB, int B,
                                                         int* __restrict__ glens,
                                                         int* __restrict__ gstart,
                                                         int* __restrict__ edge_sorted,
                                                         const float* __restrict__ W1,
                                                         const float* __restrict__ W2,
                                                         const float* __restrict__ W3,
                                                         __hip_bfloat16* __restrict__ Wp1,
                                                         __hip_bfloat16* __restrict__ Wp2,
                                                         __hip_bfloat16* __restrict__ Wp3) {
    int t = threadIdx.x;
    if ((int)blockIdx.x >= B) {
        // folded weight prep (independent work)
        int i = ((int)blockIdx.x - B) * 256 + t;
        if (i < 16384) {                      // W1: 128x128
            int k = i >> 7, n = i & 127;
            Wp1[(((k >> 3) * 128) + n) * 8 + (k & 7)] = __float2bfloat16(W1[i]);
        } else if (i < 24576) {               // W2: 128x64
            int j = i - 16384;
            int k = j >> 6, n = j & 63;
            Wp2[(((k >> 3) * 64) + n) * 8 + (k & 7)] = __float2bfloat16(W2[j]);
        } else if (i < PREPN) {               // W3: 64x64
            int j = i - 24576;
            int k = j >> 6, n = j & 63;
            Wp3[(((k >> 3) * 64) + n) * 8 + (k & 7)] = __float2bfloat16(W3[j]);
        }
        return;
    }
    extern __shared__ int lds[];
    int* hist  = lds;                 // NB
    int* lbase = lds + NB;            // NB
    int* sortd = lds + 2 * NB;        // EPB
    int blk = blockIdx.x;
    int e0 = blk * EPB;
    int cnt = E - e0;
    if (cnt > EPB) cnt = EPB;

    for (int i = t; i < NB; i += 256) hist[i] = 0;
    __syncthreads();
    for (int i = t; i < cnt; i += 256) {
        int dst = ei[E + e0 + i];
        atomicAdd(&hist[dst >> BKT_SHIFT], 1);
    }
    __syncthreads();
    for (int i = t; i < NB; i += 256) lbase[i] = hist[i];
    __syncthreads();
    block_excl_scan(lbase, NB, t);
    __syncthreads();
    for (int i = t; i < NB; i += 256) {
        glens[(size_t)blk * NB + i] = hist[i];
        gstart[(size_t)blk * NB + i] = lbase[i];
    }
    __syncthreads();
    for (int i = t; i < cnt; i += 256) {
        int src = ei[e0 + i];
        int dst = ei[E + e0 + i];
        int pos = atomicAdd(&lbase[dst >> BKT_SHIFT], 1);
        sortd[pos] = (src << BKT_SHIFT) | (dst & (BKT_NODES - 1));
    }
    __syncthreads();
    for (int i = t; i < cnt; i += 256) edge_sorted[e0 + i] = sortd[i];
}

// One block per bucket: 256 threads sum over chunk dim, wave+LDS reduce.
__global__ __launch_bounds__(256) void btot_kernel(const int* __restrict__ glens, int NB, int B,
                                                   int* __restrict__ btot) {
    __shared__ int wsum[4];
    int b = blockIdx.x;
    int t = threadIdx.x;
    int lane = t & 63, wv = t >> 6;
    int sum = 0;
    for (int blk = t; blk < B; blk += 256) sum += glens[(size_t)blk * NB + b];
#pragma unroll
    for (int off = 32; off > 0; off >>= 1) sum += __shfl_down(sum, off, 64);
    if (lane == 0) wsum[wv] = sum;
    __syncthreads();
    if (t == 0) btot[b] = wsum[0] + wsum[1] + wsum[2] + wsum[3];
}

// single block: load btot -> scan -> bbase
__global__ __launch_bounds__(256) void scan_nb_kernel(const int* __restrict__ btot, int NB,
                                                      int* __restrict__ bbase) {
    extern __shared__ int arr[];
    int t = threadIdx.x;
    for (int i = t; i < NB; i += 256) arr[i] = btot[i];
    __syncthreads();
    block_excl_scan(arr, NB, t);
    __syncthreads();
    for (int i = t; i < NB; i += 256) bbase[i] = arr[i];
}

// One block per bucket: gather runs, counting-sort by local node, write CSR
// segment + row_ptr + dinv.
__global__ __launch_bounds__(256) void csr_build_kernel(const int* __restrict__ edge_sorted,
                                                        const int* __restrict__ glens,
                                                        const int* __restrict__ gstart,
                                                        const int* __restrict__ bbase,
                                                        int NB, int B, int N, int E,
                                                        int* __restrict__ row_ptr,
                                                        float* __restrict__ dinv,
                                                        int* __restrict__ csr) {
    __shared__ int lruns[512];
    __shared__ int loffs[512];
    __shared__ int sdeg[BKT_NODES];
    __shared__ int scur[BKT_NODES];
    __shared__ int raw[LCAP];
    __shared__ int srt[LCAP];
    int b = blockIdx.x;
    int t = threadIdx.x;

    for (int i = t; i < 512; i += 256) {
        int v = (i < B) ? glens[(size_t)i * NB + b] : 0;
        lruns[i] = v;
        loffs[i] = v;
    }
    if (t < BKT_NODES) sdeg[t] = 0;
    __syncthreads();
    block_excl_scan(loffs, B, t);
    __syncthreads();
    int cnt = loffs[B - 1] + lruns[B - 1];
    if (cnt > LCAP) cnt = LCAP;

    for (int r = t; r < B; r += 256) {
        int len = lruns[r];
        if (len) {
            int off = loffs[r];
            int st = r * EPB + gstart[(size_t)r * NB + b];
            for (int k = 0; k < len; ++k) {
                int p = off + k;
                if (p < LCAP) raw[p] = edge_sorted[st + k];
            }
        }
    }
    __syncthreads();

    for (int i = t; i < cnt; i += 256) atomicAdd(&sdeg[raw[i] & (BKT_NODES - 1)], 1);
    __syncthreads();
    int base = bbase[b];
    if (t < BKT_NODES) {
        int ssum = 0;
        for (int i = 0; i < t; ++i) ssum += sdeg[i];
        scur[t] = ssum;
        int node = b * BKT_NODES + t;
        if (node < N) {
            row_ptr[node] = base + ssum;
            dinv[node] = rsqrtf((float)(sdeg[t] + 1));   // +1 self loop
        }
    }
    if (b == 0 && t == 0) row_ptr[N] = E;
    __syncthreads();
    for (int i = t; i < cnt; i += 256) {
        int p = raw[i];
        int pos = atomicAdd(&scur[p & (BKT_NODES - 1)], 1);
        srt[pos] = p >> BKT_SHIFT;
    }
    __syncthreads();
    for (int i = t; i < cnt; i += 256) csr[base + i] = srt[i];
}

// --------------------------- MFMA GEMM -------------------------------------
// C[r][:] = dinv[r] * (A[r][:] @ W)   stored bf16 (pre-scaled rows).

template <int DI, int DO, bool AF32>
__global__ __launch_bounds__(256) void mfma_gemm_kernel(const void* __restrict__ Av,
                                                        const __hip_bfloat16* __restrict__ Wp,
                                                        const float* __restrict__ dinv,
                                                        __hip_bfloat16* __restrict__ C, int N) {
    constexpr int NT = DO / 16;
    int t = threadIdx.x;
    int wave = t >> 6, lane = t & 63;
    int q = lane >> 4, l16 = lane & 15;
    int rbase = blockIdx.x * 64 + wave * 16;
    int row = rbase + l16;
    int rowc = row < N ? row : N - 1;

    f32x4 acc[NT];
#pragma unroll
    for (int i = 0; i < NT; ++i) acc[i] = (f32x4){0.f, 0.f, 0.f, 0.f};

#pragma unroll
    for (int kt = 0; kt < DI / 32; ++kt) {
        int k0 = kt * 32 + q * 8;
        short8 afrag;
        if (AF32) {
            const float* A = (const float*)Av;
            const float* ap = A + (size_t)rowc * DI + k0;
            float4 lo = *(const float4*)ap;
            float4 hi = *(const float4*)(ap + 4);
            afrag[0] = f2bs(lo.x); afrag[1] = f2bs(lo.y);
            afrag[2] = f2bs(lo.z); afrag[3] = f2bs(lo.w);
            afrag[4] = f2bs(hi.x); afrag[5] = f2bs(hi.y);
            afrag[6] = f2bs(hi.z); afrag[7] = f2bs(hi.w);
        } else {
            const __hip_bfloat16* A = (const __hip_bfloat16*)Av;
            afrag = *(const short8*)(A + (size_t)rowc * DI + k0);
        }
        const short8* wrow = (const short8*)(Wp + (size_t)(kt * 4 + q) * DO * 8);
#pragma unroll
        for (int tt = 0; tt < NT; ++tt) {
            short8 bfrag = wrow[tt * 16 + l16];
            acc[tt] = __builtin_amdgcn_mfma_f32_16x16x32_bf16(afrag, bfrag, acc[tt], 0, 0, 0);
        }
    }
    // C/D layout: col = lane&15, row = (lane>>4)*4 + reg
#pragma unroll
    for (int r = 0; r < 4; ++r) {
        int gr = rbase + q * 4 + r;
        if (gr < N) {
            float dv = dinv[gr];
#pragma unroll
            for (int tt = 0; tt < NT; ++tt)
                C[(size_t)gr * DO + tt * 16 + l16] = __float2bfloat16(acc[tt][r] * dv);
        }
    }
}

// --------------------------- aggregation -----------------------------------
// Rows pre-scaled by dinv[src]:  out = relu( dvi*(r_self + sum r_src) + b ).

// D=128: quarter-wave per edge (4 in flight), 16 lanes x uint4 = 256 B/row.
__global__ __launch_bounds__(256) void agg128_kernel(const uint4* __restrict__ tmp,
                                                     const float* __restrict__ bias,
                                                     const float* __restrict__ dinv,
                                                     const int* __restrict__ row_ptr,
                                                     const int* __restrict__ csr_src,
                                                     uint4* __restrict__ outp, int N) {
    int lane = threadIdx.x & 63;
    int q = lane >> 4, sub = lane & 15;
    int node = blockIdx.x * 4 + (threadIdx.x >> 6);
    if (node >= N) return;
    float dvi = dinv[node];
    float a0 = 0, a1 = 0, a2 = 0, a3 = 0, a4 = 0, a5 = 0, a6 = 0, a7 = 0;
    if (q == 0) {
        uint4 sv = tmp[(size_t)node * 16 + sub];
        float2 p0 = bpair(sv.x), p1 = bpair(sv.y), p2 = bpair(sv.z), p3 = bpair(sv.w);
        a0 = p0.x; a1 = p0.y; a2 = p1.x; a3 = p1.y;
        a4 = p2.x; a5 = p2.y; a6 = p3.x; a7 = p3.y;
    }
    int beg = row_ptr[node], end = row_ptr[node + 1];
    for (int j = beg; j < end; j += 64) {
        int m = end - j;
        if (m > 64) m = 64;
        int s = (lane < m) ? csr_src[j + lane] : 0;
        int iters = (m + 3) >> 2;
        for (int k = 0; k < iters; ++k) {
            int e = 4 * k + q;
            int ec = (e < m) ? e : 0;
            int sk = __shfl(s, ec, 64);
            uint4 v = tmp[(size_t)sk * 16 + sub];
            if (e < m) {
                float2 p0 = bpair(v.x), p1 = bpair(v.y), p2 = bpair(v.z), p3 = bpair(v.w);
                a0 += p0.x; a1 += p0.y; a2 += p1.x; a3 += p1.y;
                a4 += p2.x; a5 += p2.y; a6 += p3.x; a7 += p3.y;
            }
        }
    }
    a0 += __shfl_xor(a0, 16, 64); a1 += __shfl_xor(a1, 16, 64);
    a2 += __shfl_xor(a2, 16, 64); a3 += __shfl_xor(a3, 16, 64);
    a4 += __shfl_xor(a4, 16, 64); a5 += __shfl_xor(a5, 16, 64);
    a6 += __shfl_xor(a6, 16, 64); a7 += __shfl_xor(a7, 16, 64);
    a0 += __shfl_xor(a0, 32, 64); a1 += __shfl_xor(a1, 32, 64);
    a2 += __shfl_xor(a2, 32, 64); a3 += __shfl_xor(a3, 32, 64);
    a4 += __shfl_xor(a4, 32, 64); a5 += __shfl_xor(a5, 32, 64);
    a6 += __shfl_xor(a6, 32, 64); a7 += __shfl_xor(a7, 32, 64);
    if (q == 0) {
        float4 b0 = *(const float4*)&bias[sub * 8];
        float4 b1 = *(const float4*)&bias[sub * 8 + 4];
        uint4 o;
        o.x = packbf(fmaxf(dvi * a0 + b0.x, 0.f), fmaxf(dvi * a1 + b0.y, 0.f));
        o.y = packbf(fmaxf(dvi * a2 + b0.z, 0.f), fmaxf(dvi * a3 + b0.w, 0.f));
        o.z = packbf(fmaxf(dvi * a4 + b1.x, 0.f), fmaxf(dvi * a5 + b1.y, 0.f));
        o.w = packbf(fmaxf(dvi * a6 + b1.z, 0.f), fmaxf(dvi * a7 + b1.w, 0.f));
        outp[(size_t)node * 16 + sub] = o;
    }
}

// D=64: eighth-wave per edge (8 in flight), 8 lanes x uint4 = 128 B/row.
__global__ __launch_bounds__(256) void agg64_kernel(const uint4* __restrict__ tmp,
                                                    const float* __restrict__ bias,
                                                    const float* __restrict__ dinv,
                                                    const int* __restrict__ row_ptr,
                                                    const int* __restrict__ csr_src,
                                                    uint4* __restrict__ outp, int N) {
    int lane = threadIdx.x & 63;
    int o8 = lane >> 3, sub = lane & 7;
    int node = blockIdx.x * 4 + (threadIdx.x >> 6);
    if (node >= N) return;
    float dvi = dinv[node];
    float a0 = 0, a1 = 0, a2 = 0, a3 = 0, a4 = 0, a5 = 0, a6 = 0, a7 = 0;
    if (o8 == 0) {
        uint4 sv = tmp[(size_t)node * 8 + sub];
        float2 p0 = bpair(sv.x), p1 = bpair(sv.y), p2 = bpair(sv.z), p3 = bpair(sv.w);
        a0 = p0.x; a1 = p0.y; a2 = p1.x; a3 = p1.y;
        a4 = p2.x; a5 = p2.y; a6 = p3.x; a7 = p3.y;
    }
    int beg = row_ptr[node], end = row_ptr[node + 1];
    for (int j = beg; j < end; j += 64) {
        int m = end - j;
        if (m > 64) m = 64;
        int s = (lane < m) ? csr_src[j + lane] : 0;
        int iters = (m + 7) >> 3;
        for (int k = 0; k < iters; ++k) {
            int e = 8 * k + o8;
            int ec = (e < m) ? e : 0;
            int sk = __shfl(s, ec, 64);
            uint4 v = tmp[(size_t)sk * 8 + sub];
            if (e < m) {
                float2 p0 = bpair(v.x), p1 = bpair(v.y), p2 = bpair(v.z), p3 = bpair(v.w);
                a0 += p0.x; a1 += p0.y; a2 += p1.x; a3 += p1.y;
                a4 += p2.x; a5 += p2.y; a6 += p3.x; a7 += p3.y;
            }
        }
    }
    a0 += __shfl_xor(a0, 8, 64); a1 += __shfl_xor(a1, 8, 64);
    a2 += __shfl_xor(a2, 8, 64); a3 += __shfl_xor(a3, 8, 64);
    a4 += __shfl_xor(a4, 8, 64); a5 += __shfl_xor(a5, 8, 64);
    a6 += __shfl_xor(a6, 8, 64); a7 += __shfl_xor(a7, 8, 64);
    a0 += __shfl_xor(a0, 16, 64); a1 += __shfl_xor(a1, 16, 64);
    a2 += __shfl_xor(a2, 16, 64); a3 += __shfl_xor(a3, 16, 64);
    a4 += __shfl_xor(a4, 16, 64); a5 += __shfl_xor(a5, 16, 64);
    a6 += __shfl_xor(a6, 16, 64); a7 += __shfl_xor(a7, 16, 64);
    a0 += __shfl_xor(a0, 32, 64); a1 += __shfl_xor(a1, 32, 64);
    a2 += __shfl_xor(a2, 32, 64); a3 += __shfl_xor(a3, 32, 64);
    a4 += __shfl_xor(a4, 32, 64); a5 += __shfl_xor(a5, 32, 64);
    a6 += __shfl_xor(a6, 32, 64); a7 += __shfl_xor(a7, 32, 64);
    if (o8 == 0) {
        float4 b0 = *(const float4*)&bias[sub * 8];
        float4 b1 = *(const float4*)&bias[sub * 8 + 4];
        uint4 o;
        o.x = packbf(fmaxf(dvi * a0 + b0.x, 0.f), fmaxf(dvi * a1 + b0.y, 0.f));
        o.y = packbf(fmaxf(dvi * a2 + b0.z, 0.f), fmaxf(dvi * a3 + b0.w, 0.f));
        o.z = packbf(fmaxf(dvi * a4 + b1.x, 0.f), fmaxf(dvi * a5 + b1.y, 0.f));
        o.w = packbf(fmaxf(dvi * a6 + b1.z, 0.f), fmaxf(dvi * a7 + b1.w, 0.f));
        outp[(size_t)node * 8 + sub] = o;
    }
}

// --------------------------- head ------------------------------------------

__global__ __launch_bounds__(256) void head_kernel(const unsigned* __restrict__ h,
                                                   const float* __restrict__ protos,
                                                   const float* __restrict__ Wf0,
                                                   const float* __restrict__ bf0,
                                                   const float* __restrict__ Wf1,
                                                   const float* __restrict__ bf1,
                                                   const int* __restrict__ y,
                                                   float* __restrict__ out, int N) {
    __shared__ float Hl[64 * 65];
    __shared__ float Pl[16 * 65];
    __shared__ float hh[64];
    __shared__ float pp[16];
    __shared__ float sim[64 * 17];
    __shared__ float Wf0l[128];
    __shared__ float bf0l[8];
    __shared__ float Wf1l[8];
    __shared__ float bf1l;
    int t = threadIdx.x;
    int n0 = blockIdx.x * 64;

    for (int idx = t; idx < 64 * 32; idx += 256) {
        int r = idx >> 5, c = idx & 31;
        int g = n0 + r;
        unsigned u = (g < N) ? h[(size_t)g * 32 + c] : 0u;
        float2 v = bpair(u);
        Hl[r * 65 + 2 * c] = v.x;
        Hl[r * 65 + 2 * c + 1] = v.y;
    }
    for (int idx = t; idx < 16 * 64; idx += 256) {
        int r = idx >> 6, c = idx & 63;
        Pl[r * 65 + c] = protos[idx];
    }
    if (t < 128) Wf0l[t] = Wf0[t];
    if (t < 8) { bf0l[t] = bf0[t]; Wf1l[t] = Wf1[t]; }
    if (t == 0) bf1l = bf1[0];
    __syncthreads();

    if (t < 64) {
        float s = 0.0f;
        for (int k = 0; k < 64; ++k) { float v = Hl[t * 65 + k]; s += v * v; }
        hh[t] = s;
    } else if (t < 80) {
        int p = t - 64;
        float s = 0.0f;
        for (int k = 0; k < 64; ++k) { float v = Pl[p * 65 + k]; s += v * v; }
        pp[p] = s;
    }
    __syncthreads();

    {
        int node = t & 63;
        int p4 = (t >> 6) * 4;
        float d0 = 0, d1 = 0, d2 = 0, d3 = 0;
        for (int k = 0; k < 64; ++k) {
            float hv = Hl[node * 65 + k];
            d0 += hv * Pl[(p4 + 0) * 65 + k];
            d1 += hv * Pl[(p4 + 1) * 65 + k];
            d2 += hv * Pl[(p4 + 2) * 65 + k];
            d3 += hv * Pl[(p4 + 3) * 65 + k];
        }
        float hhv = hh[node];
        float dd[4] = {d0, d1, d2, d3};
#pragma unroll
        for (int j = 0; j < 4; ++j) {
            float q = hhv + pp[p4 + j] - 2.0f * dd[j];
            q = q > 0.0f ? q : 0.0f;
            sim[node * 17 + p4 + j] = logf((q + 1.0f) / (q + 1e-4f));
        }
    }
    __syncthreads();

    if (t < 64) {
        int g = n0 + t;
        if (g < N) {
            float zacc = bf1l;
#pragma unroll
            for (int o = 0; o < 8; ++o) {
                float s = bf0l[o];
#pragma unroll
                for (int i2 = 0; i2 < 16; ++i2) s += sim[t * 17 + i2] * Wf0l[i2 * 8 + o];
                float gz = 0.5f * s * (1.0f + erff(s * 0.70710678118654752f));
                zacc += gz * Wf1l[o];
            }
            out[g] = 1.0f / (1.0f + expf(-zacc));
        }
    } else if (t < 128) {
        int g = n0 + (t - 64);
        if (g < N) out[N + g] = (float)y[g];
    }
}

// ---------------------------------------------------------------------------

extern "C" void kernel_launch(void* const* d_in, const int* in_sizes, int n_in,
                              void* d_out, int out_size, void* d_ws, size_t ws_size,
                              hipStream_t stream) {
    const float* x   = (const float*)d_in[0];
    const int*   ei  = (const int*)d_in[1];
    const int*   y   = (const int*)d_in[2];
    const float* W1  = (const float*)d_in[3];
    const float* b1  = (const float*)d_in[4];
    const float* W2  = (const float*)d_in[5];
    const float* b2  = (const float*)d_in[6];
    const float* W3  = (const float*)d_in[7];
    const float* b3  = (const float*)d_in[8];
    const float* pr  = (const float*)d_in[9];
    const float* Wf0 = (const float*)d_in[10];
    const float* bf0 = (const float*)d_in[11];
    const float* Wf1 = (const float*)d_in[12];
    const float* bf1 = (const float*)d_in[13];
    float* outp = (float*)d_out;

    const int N = in_sizes[2];       // 50000
    const int E = in_sizes[1] / 2;   // 800000
    const int NB = (N + BKT_NODES - 1) / BKT_NODES;   // 1563
    const int B = (E + EPB - 1) / EPB;                // 391 (<=512)

    char* w = (char*)d_ws;
    auto carve = [&](size_t bytes) {
        char* p = w;
        w += (bytes + 511) & ~(size_t)511;
        return p;
    };
    int*   glens   = (int*)carve((size_t)B * NB * 4);
    int*   gstart  = (int*)carve((size_t)B * NB * 4);
    int*   btot    = (int*)carve((size_t)NB * 4);
    int*   bbase   = (int*)carve((size_t)NB * 4);
    int*   esort   = (int*)carve((size_t)B * EPB * 4);
    int*   row_ptr = (int*)carve((size_t)(N + 1) * 4);
    float* dinv    = (float*)carve((size_t)N * 4);
    int*   csr     = (int*)carve((size_t)E * 4);
    __hip_bfloat16* Wp1 = (__hip_bfloat16*)carve(16384 * 2);
    __hip_bfloat16* Wp2 = (__hip_bfloat16*)carve(8192 * 2);
    __hip_bfloat16* Wp3 = (__hip_bfloat16*)carve(4096 * 2);
    __hip_bfloat16* bufT = (__hip_bfloat16*)carve((size_t)N * 128 * 2);
    __hip_bfloat16* bufH = (__hip_bfloat16*)carve((size_t)N * 128 * 2);

    size_t sort_lds = (size_t)(2 * NB + EPB) * 4;   // ~20.7 KB
    size_t scan_lds = (size_t)NB * 4;               // ~6.3 KB

    sort_local_kernel<<<B + PREPB, 256, sort_lds, stream>>>(ei, E, NB, B, glens, gstart, esort,
                                                            W1, W2, W3, Wp1, Wp2, Wp3);
    btot_kernel<<<NB, 256, 0, stream>>>(glens, NB, B, btot);
    scan_nb_kernel<<<1, 256, scan_lds, stream>>>(btot, NB, bbase);
    csr_build_kernel<<<NB, 256, 0, stream>>>(esort, glens, gstart, bbase, NB, B, N, E,
                                             row_ptr, dinv, csr);

    // L1: x(f32,128) @ W1 -> bufT(bf16,128, dinv-prescaled); agg128 -> bufH
    mfma_gemm_kernel<128, 128, true><<<(N + 63) / 64, 256, 0, stream>>>(x, Wp1, dinv, bufT, N);
    agg128_kernel<<<(N + 3) / 4, 256, 0, stream>>>((const uint4*)bufT, b1, dinv, row_ptr, csr,
                                                   (uint4*)bufH, N);
    // L2
    mfma_gemm_kernel<128, 64, false><<<(N + 63) / 64, 256, 0, stream>>>(bufH, Wp2, dinv, bufT, N);
    agg64_kernel<<<(N + 3) / 4, 256, 0, stream>>>((const uint4*)bufT, b2, dinv, row_ptr, csr,
                                                  (uint4*)bufH, N);
    // L3
    mfma_gemm_kernel<64, 64, false><<<(N + 63) / 64, 256, 0, stream>>>(bufH, Wp3, dinv, bufT, N);
    agg64_kernel<<<(N + 3) / 4, 256, 0, stream>>>((const uint4*)bufT, b3, dinv, row_ptr, csr,
                                                  (uint4*)bufH, N);
    // Head
    head_kernel<<<(N + 63) / 64, 256, 0, stream>>>((const unsigned*)bufH, pr, Wf0, bf0, Wf1, bf1,
                                                   y, outp, N);
}

// Round 7
// 246.144 us; speedup vs baseline: 1.4121x; 1.0526x over previous
//
#include <hip/hip_runtime.h>
#include <hip/hip_bf16.h>
#include <math.h>

// ---------------------------------------------------------------------------
// SLADGNN round 7: static-base CSR segments (bucket b owns slots [b*1024,
// b*1024+cnt) -> btot/scan kernels deleted; 13 -> 9 dispatches). Round-6
// sort/csr/gemm/agg structure otherwise unchanged.
// ---------------------------------------------------------------------------

typedef __attribute__((ext_vector_type(8))) short short8;
typedef __attribute__((ext_vector_type(4))) float f32x4;

#define BKT_SHIFT 5
#define BKT_NODES 32
#define EPB 2048        // edges per sort_local block (391 blocks)
#define LCAP 1024       // per-bucket CSR slot capacity (mean 512, +22 sigma)
#define PREPN 28672     // prep_w elements
#define PREPB 112       // prep_w blocks

__device__ __forceinline__ short f2bs(float x) {
    __hip_bfloat16 b = __float2bfloat16(x);
    return *reinterpret_cast<short*>(&b);
}
__device__ __forceinline__ float2 bpair(unsigned u) {
    float lo = __uint_as_float(u << 16);
    float hi = __uint_as_float(u & 0xffff0000u);
    return make_float2(lo, hi);
}
__device__ __forceinline__ unsigned packbf(float a, float b) {
    unsigned la = (unsigned)(unsigned short)f2bs(a);
    unsigned hb = (unsigned)(unsigned short)f2bs(b);
    return la | (hb << 16);
}

// Block-wide exclusive scan of arr[0..n) in LDS. 2 barriers per 256-chunk.
__device__ __forceinline__ void block_excl_scan(int* __restrict__ arr, int n, int t) {
    __shared__ int wsums[4];
    int lane = t & 63, wv = t >> 6;
    int carry = 0;
    for (int c0 = 0; c0 < n; c0 += 256) {
        int i = c0 + t;
        int v = (i < n) ? arr[i] : 0;
        int orig = v;
#pragma unroll
        for (int off = 1; off < 64; off <<= 1) {
            int u = __shfl_up(v, off, 64);
            if (lane >= off) v += u;
        }
        if (lane == 63) wsums[wv] = v;
        __syncthreads();
        int w0 = wsums[0], w1 = wsums[1], w2 = wsums[2], w3 = wsums[3];
        int woff = (wv > 0 ? w0 : 0) + (wv > 1 ? w1 : 0) + (wv > 2 ? w2 : 0);
        int tot = w0 + w1 + w2 + w3;
        __syncthreads();
        if (i < n) arr[i] = carry + woff + (v - orig);
        carry += tot;
    }
}

// --------------------- CSR build (deterministic, no global atomics) --------

__global__ __launch_bounds__(256) void sort_local_kernel(const int* __restrict__ ei, int E,
                                                         int NB, int B,
                                                         int* __restrict__ glens,
                                                         int* __restrict__ gstart,
                                                         int* __restrict__ edge_sorted,
                                                         const float* __restrict__ W1,
                                                         const float* __restrict__ W2,
                                                         const float* __restrict__ W3,
                                                         __hip_bfloat16* __restrict__ Wp1,
                                                         __hip_bfloat16* __restrict__ Wp2,
                                                         __hip_bfloat16* __restrict__ Wp3) {
    int t = threadIdx.x;
    if ((int)blockIdx.x >= B) {
        // folded weight prep (independent work)
        int i = ((int)blockIdx.x - B) * 256 + t;
        if (i < 16384) {                      // W1: 128x128
            int k = i >> 7, n = i & 127;
            Wp1[(((k >> 3) * 128) + n) * 8 + (k & 7)] = __float2bfloat16(W1[i]);
        } else if (i < 24576) {               // W2: 128x64
            int j = i - 16384;
            int k = j >> 6, n = j & 63;
            Wp2[(((k >> 3) * 64) + n) * 8 + (k & 7)] = __float2bfloat16(W2[j]);
        } else if (i < PREPN) {               // W3: 64x64
            int j = i - 24576;
            int k = j >> 6, n = j & 63;
            Wp3[(((k >> 3) * 64) + n) * 8 + (k & 7)] = __float2bfloat16(W3[j]);
        }
        return;
    }
    extern __shared__ int lds[];
    int* hist  = lds;                 // NB
    int* lbase = lds + NB;            // NB
    int* sortd = lds + 2 * NB;        // EPB
    int blk = blockIdx.x;
    int e0 = blk * EPB;
    int cnt = E - e0;
    if (cnt > EPB) cnt = EPB;

    for (int i = t; i < NB; i += 256) hist[i] = 0;
    __syncthreads();
    for (int i = t; i < cnt; i += 256) {
        int dst = ei[E + e0 + i];
        atomicAdd(&hist[dst >> BKT_SHIFT], 1);
    }
    __syncthreads();
    for (int i = t; i < NB; i += 256) lbase[i] = hist[i];
    __syncthreads();
    block_excl_scan(lbase, NB, t);
    __syncthreads();
    for (int i = t; i < NB; i += 256) {
        glens[(size_t)blk * NB + i] = hist[i];
        gstart[(size_t)blk * NB + i] = lbase[i];
    }
    __syncthreads();
    for (int i = t; i < cnt; i += 256) {
        int src = ei[e0 + i];
        int dst = ei[E + e0 + i];
        int pos = atomicAdd(&lbase[dst >> BKT_SHIFT], 1);
        sortd[pos] = (src << BKT_SHIFT) | (dst & (BKT_NODES - 1));
    }
    __syncthreads();
    for (int i = t; i < cnt; i += 256) edge_sorted[e0 + i] = sortd[i];
}

// One block per bucket: gather runs, counting-sort by local node, write CSR
// segment at static base b*LCAP + row_beg/row_end + dinv. No scan chain.
__global__ __launch_bounds__(256) void csr_build_kernel(const int* __restrict__ edge_sorted,
                                                        const int* __restrict__ glens,
                                                        const int* __restrict__ gstart,
                                                        int NB, int B, int N,
                                                        int* __restrict__ row_beg,
                                                        int* __restrict__ row_end,
                                                        float* __restrict__ dinv,
                                                        int* __restrict__ csr) {
    __shared__ int lruns[512];
    __shared__ int loffs[512];
    __shared__ int sdeg[BKT_NODES];
    __shared__ int scur[BKT_NODES];
    __shared__ int raw[LCAP];
    __shared__ int srt[LCAP];
    int b = blockIdx.x;
    int t = threadIdx.x;

    for (int i = t; i < 512; i += 256) {
        int v = (i < B) ? glens[(size_t)i * NB + b] : 0;
        lruns[i] = v;
        loffs[i] = v;
    }
    if (t < BKT_NODES) sdeg[t] = 0;
    __syncthreads();
    block_excl_scan(loffs, B, t);
    __syncthreads();
    int cnt = loffs[B - 1] + lruns[B - 1];
    if (cnt > LCAP) cnt = LCAP;

    for (int r = t; r < B; r += 256) {
        int len = lruns[r];
        if (len) {
            int off = loffs[r];
            int st = r * EPB + gstart[(size_t)r * NB + b];
            for (int k = 0; k < len; ++k) {
                int p = off + k;
                if (p < LCAP) raw[p] = edge_sorted[st + k];
            }
        }
    }
    __syncthreads();

    for (int i = t; i < cnt; i += 256) atomicAdd(&sdeg[raw[i] & (BKT_NODES - 1)], 1);
    __syncthreads();
    int base = b * LCAP;
    if (t < BKT_NODES) {
        int ssum = 0;
        for (int i = 0; i < t; ++i) ssum += sdeg[i];
        scur[t] = ssum;
        int node = b * BKT_NODES + t;
        if (node < N) {
            row_beg[node] = base + ssum;
            row_end[node] = base + ssum + sdeg[t];
            dinv[node] = rsqrtf((float)(sdeg[t] + 1));   // +1 self loop
        }
    }
    __syncthreads();
    for (int i = t; i < cnt; i += 256) {
        int p = raw[i];
        int pos = atomicAdd(&scur[p & (BKT_NODES - 1)], 1);
        srt[pos] = p >> BKT_SHIFT;
    }
    __syncthreads();
    for (int i = t; i < cnt; i += 256) csr[base + i] = srt[i];
}

// --------------------------- MFMA GEMM -------------------------------------
// C[r][:] = dinv[r] * (A[r][:] @ W)   stored bf16 (pre-scaled rows).

template <int DI, int DO, bool AF32>
__global__ __launch_bounds__(256) void mfma_gemm_kernel(const void* __restrict__ Av,
                                                        const __hip_bfloat16* __restrict__ Wp,
                                                        const float* __restrict__ dinv,
                                                        __hip_bfloat16* __restrict__ C, int N) {
    constexpr int NT = DO / 16;
    int t = threadIdx.x;
    int wave = t >> 6, lane = t & 63;
    int q = lane >> 4, l16 = lane & 15;
    int rbase = blockIdx.x * 64 + wave * 16;
    int row = rbase + l16;
    int rowc = row < N ? row : N - 1;

    f32x4 acc[NT];
#pragma unroll
    for (int i = 0; i < NT; ++i) acc[i] = (f32x4){0.f, 0.f, 0.f, 0.f};

#pragma unroll
    for (int kt = 0; kt < DI / 32; ++kt) {
        int k0 = kt * 32 + q * 8;
        short8 afrag;
        if (AF32) {
            const float* A = (const float*)Av;
            const float* ap = A + (size_t)rowc * DI + k0;
            float4 lo = *(const float4*)ap;
            float4 hi = *(const float4*)(ap + 4);
            afrag[0] = f2bs(lo.x); afrag[1] = f2bs(lo.y);
            afrag[2] = f2bs(lo.z); afrag[3] = f2bs(lo.w);
            afrag[4] = f2bs(hi.x); afrag[5] = f2bs(hi.y);
            afrag[6] = f2bs(hi.z); afrag[7] = f2bs(hi.w);
        } else {
            const __hip_bfloat16* A = (const __hip_bfloat16*)Av;
            afrag = *(const short8*)(A + (size_t)rowc * DI + k0);
        }
        const short8* wrow = (const short8*)(Wp + (size_t)(kt * 4 + q) * DO * 8);
#pragma unroll
        for (int tt = 0; tt < NT; ++tt) {
            short8 bfrag = wrow[tt * 16 + l16];
            acc[tt] = __builtin_amdgcn_mfma_f32_16x16x32_bf16(afrag, bfrag, acc[tt], 0, 0, 0);
        }
    }
    // C/D layout: col = lane&15, row = (lane>>4)*4 + reg
#pragma unroll
    for (int r = 0; r < 4; ++r) {
        int gr = rbase + q * 4 + r;
        if (gr < N) {
            float dv = dinv[gr];
#pragma unroll
            for (int tt = 0; tt < NT; ++tt)
                C[(size_t)gr * DO + tt * 16 + l16] = __float2bfloat16(acc[tt][r] * dv);
        }
    }
}

// --------------------------- aggregation -----------------------------------
// Rows pre-scaled by dinv[src]:  out = relu( dvi*(r_self + sum r_src) + b ).

// D=128: quarter-wave per edge (4 in flight), 16 lanes x uint4 = 256 B/row.
__global__ __launch_bounds__(256) void agg128_kernel(const uint4* __restrict__ tmp,
                                                     const float* __restrict__ bias,
                                                     const float* __restrict__ dinv,
                                                     const int* __restrict__ row_beg,
                                                     const int* __restrict__ row_end,
                                                     const int* __restrict__ csr_src,
                                                     uint4* __restrict__ outp, int N) {
    int lane = threadIdx.x & 63;
    int q = lane >> 4, sub = lane & 15;
    int node = blockIdx.x * 4 + (threadIdx.x >> 6);
    if (node >= N) return;
    float dvi = dinv[node];
    float a0 = 0, a1 = 0, a2 = 0, a3 = 0, a4 = 0, a5 = 0, a6 = 0, a7 = 0;
    if (q == 0) {
        uint4 sv = tmp[(size_t)node * 16 + sub];
        float2 p0 = bpair(sv.x), p1 = bpair(sv.y), p2 = bpair(sv.z), p3 = bpair(sv.w);
        a0 = p0.x; a1 = p0.y; a2 = p1.x; a3 = p1.y;
        a4 = p2.x; a5 = p2.y; a6 = p3.x; a7 = p3.y;
    }
    int beg = row_beg[node], end = row_end[node];
    for (int j = beg; j < end; j += 64) {
        int m = end - j;
        if (m > 64) m = 64;
        int s = (lane < m) ? csr_src[j + lane] : 0;
        int iters = (m + 3) >> 2;
        for (int k = 0; k < iters; ++k) {
            int e = 4 * k + q;
            int ec = (e < m) ? e : 0;
            int sk = __shfl(s, ec, 64);
            uint4 v = tmp[(size_t)sk * 16 + sub];
            if (e < m) {
                float2 p0 = bpair(v.x), p1 = bpair(v.y), p2 = bpair(v.z), p3 = bpair(v.w);
                a0 += p0.x; a1 += p0.y; a2 += p1.x; a3 += p1.y;
                a4 += p2.x; a5 += p2.y; a6 += p3.x; a7 += p3.y;
            }
        }
    }
    a0 += __shfl_xor(a0, 16, 64); a1 += __shfl_xor(a1, 16, 64);
    a2 += __shfl_xor(a2, 16, 64); a3 += __shfl_xor(a3, 16, 64);
    a4 += __shfl_xor(a4, 16, 64); a5 += __shfl_xor(a5, 16, 64);
    a6 += __shfl_xor(a6, 16, 64); a7 += __shfl_xor(a7, 16, 64);
    a0 += __shfl_xor(a0, 32, 64); a1 += __shfl_xor(a1, 32, 64);
    a2 += __shfl_xor(a2, 32, 64); a3 += __shfl_xor(a3, 32, 64);
    a4 += __shfl_xor(a4, 32, 64); a5 += __shfl_xor(a5, 32, 64);
    a6 += __shfl_xor(a6, 32, 64); a7 += __shfl_xor(a7, 32, 64);
    if (q == 0) {
        float4 b0 = *(const float4*)&bias[sub * 8];
        float4 b1 = *(const float4*)&bias[sub * 8 + 4];
        uint4 o;
        o.x = packbf(fmaxf(dvi * a0 + b0.x, 0.f), fmaxf(dvi * a1 + b0.y, 0.f));
        o.y = packbf(fmaxf(dvi * a2 + b0.z, 0.f), fmaxf(dvi * a3 + b0.w, 0.f));
        o.z = packbf(fmaxf(dvi * a4 + b1.x, 0.f), fmaxf(dvi * a5 + b1.y, 0.f));
        o.w = packbf(fmaxf(dvi * a6 + b1.z, 0.f), fmaxf(dvi * a7 + b1.w, 0.f));
        outp[(size_t)node * 16 + sub] = o;
    }
}

// D=64: eighth-wave per edge (8 in flight), 8 lanes x uint4 = 128 B/row.
__global__ __launch_bounds__(256) void agg64_kernel(const uint4* __restrict__ tmp,
                                                    const float* __restrict__ bias,
                                                    const float* __restrict__ dinv,
                                                    const int* __restrict__ row_beg,
                                                    const int* __restrict__ row_end,
                                                    const int* __restrict__ csr_src,
                                                    uint4* __restrict__ outp, int N) {
    int lane = threadIdx.x & 63;
    int o8 = lane >> 3, sub = lane & 7;
    int node = blockIdx.x * 4 + (threadIdx.x >> 6);
    if (node >= N) return;
    float dvi = dinv[node];
    float a0 = 0, a1 = 0, a2 = 0, a3 = 0, a4 = 0, a5 = 0, a6 = 0, a7 = 0;
    if (o8 == 0) {
        uint4 sv = tmp[(size_t)node * 8 + sub];
        float2 p0 = bpair(sv.x), p1 = bpair(sv.y), p2 = bpair(sv.z), p3 = bpair(sv.w);
        a0 = p0.x; a1 = p0.y; a2 = p1.x; a3 = p1.y;
        a4 = p2.x; a5 = p2.y; a6 = p3.x; a7 = p3.y;
    }
    int beg = row_beg[node], end = row_end[node];
    for (int j = beg; j < end; j += 64) {
        int m = end - j;
        if (m > 64) m = 64;
        int s = (lane < m) ? csr_src[j + lane] : 0;
        int iters = (m + 7) >> 3;
        for (int k = 0; k < iters; ++k) {
            int e = 8 * k + o8;
            int ec = (e < m) ? e : 0;
            int sk = __shfl(s, ec, 64);
            uint4 v = tmp[(size_t)sk * 8 + sub];
            if (e < m) {
                float2 p0 = bpair(v.x), p1 = bpair(v.y), p2 = bpair(v.z), p3 = bpair(v.w);
                a0 += p0.x; a1 += p0.y; a2 += p1.x; a3 += p1.y;
                a4 += p2.x; a5 += p2.y; a6 += p3.x; a7 += p3.y;
            }
        }
    }
    a0 += __shfl_xor(a0, 8, 64); a1 += __shfl_xor(a1, 8, 64);
    a2 += __shfl_xor(a2, 8, 64); a3 += __shfl_xor(a3, 8, 64);
    a4 += __shfl_xor(a4, 8, 64); a5 += __shfl_xor(a5, 8, 64);
    a6 += __shfl_xor(a6, 8, 64); a7 += __shfl_xor(a7, 8, 64);
    a0 += __shfl_xor(a0, 16, 64); a1 += __shfl_xor(a1, 16, 64);
    a2 += __shfl_xor(a2, 16, 64); a3 += __shfl_xor(a3, 16, 64);
    a4 += __shfl_xor(a4, 16, 64); a5 += __shfl_xor(a5, 16, 64);
    a6 += __shfl_xor(a6, 16, 64); a7 += __shfl_xor(a7, 16, 64);
    a0 += __shfl_xor(a0, 32, 64); a1 += __shfl_xor(a1, 32, 64);
    a2 += __shfl_xor(a2, 32, 64); a3 += __shfl_xor(a3, 32, 64);
    a4 += __shfl_xor(a4, 32, 64); a5 += __shfl_xor(a5, 32, 64);
    a6 += __shfl_xor(a6, 32, 64); a7 += __shfl_xor(a7, 32, 64);
    if (o8 == 0) {
        float4 b0 = *(const float4*)&bias[sub * 8];
        float4 b1 = *(const float4*)&bias[sub * 8 + 4];
        uint4 o;
        o.x = packbf(fmaxf(dvi * a0 + b0.x, 0.f), fmaxf(dvi * a1 + b0.y, 0.f));
        o.y = packbf(fmaxf(dvi * a2 + b0.z, 0.f), fmaxf(dvi * a3 + b0.w, 0.f));
        o.z = packbf(fmaxf(dvi * a4 + b1.x, 0.f), fmaxf(dvi * a5 + b1.y, 0.f));
        o.w = packbf(fmaxf(dvi * a6 + b1.z, 0.f), fmaxf(dvi * a7 + b1.w, 0.f));
        outp[(size_t)node * 8 + sub] = o;
    }
}

// --------------------------- head ------------------------------------------

__global__ __launch_bounds__(256) void head_kernel(const unsigned* __restrict__ h,
                                                   const float* __restrict__ protos,
                                                   const float* __restrict__ Wf0,
                                                   const float* __restrict__ bf0,
                                                   const float* __restrict__ Wf1,
                                                   const float* __restrict__ bf1,
                                                   const int* __restrict__ y,
                                                   float* __restrict__ out, int N) {
    __shared__ float Hl[64 * 65];
    __shared__ float Pl[16 * 65];
    __shared__ float hh[64];
    __shared__ float pp[16];
    __shared__ float sim[64 * 17];
    __shared__ float Wf0l[128];
    __shared__ float bf0l[8];
    __shared__ float Wf1l[8];
    __shared__ float bf1l;
    int t = threadIdx.x;
    int n0 = blockIdx.x * 64;

    for (int idx = t; idx < 64 * 32; idx += 256) {
        int r = idx >> 5, c = idx & 31;
        int g = n0 + r;
        unsigned u = (g < N) ? h[(size_t)g * 32 + c] : 0u;
        float2 v = bpair(u);
        Hl[r * 65 + 2 * c] = v.x;
        Hl[r * 65 + 2 * c + 1] = v.y;
    }
    for (int idx = t; idx < 16 * 64; idx += 256) {
        int r = idx >> 6, c = idx & 63;
        Pl[r * 65 + c] = protos[idx];
    }
    if (t < 128) Wf0l[t] = Wf0[t];
    if (t < 8) { bf0l[t] = bf0[t]; Wf1l[t] = Wf1[t]; }
    if (t == 0) bf1l = bf1[0];
    __syncthreads();

    if (t < 64) {
        float s = 0.0f;
        for (int k = 0; k < 64; ++k) { float v = Hl[t * 65 + k]; s += v * v; }
        hh[t] = s;
    } else if (t < 80) {
        int p = t - 64;
        float s = 0.0f;
        for (int k = 0; k < 64; ++k) { float v = Pl[p * 65 + k]; s += v * v; }
        pp[p] = s;
    }
    __syncthreads();

    {
        int node = t & 63;
        int p4 = (t >> 6) * 4;
        float d0 = 0, d1 = 0, d2 = 0, d3 = 0;
        for (int k = 0; k < 64; ++k) {
            float hv = Hl[node * 65 + k];
            d0 += hv * Pl[(p4 + 0) * 65 + k];
            d1 += hv * Pl[(p4 + 1) * 65 + k];
            d2 += hv * Pl[(p4 + 2) * 65 + k];
            d3 += hv * Pl[(p4 + 3) * 65 + k];
        }
        float hhv = hh[node];
        float dd[4] = {d0, d1, d2, d3};
#pragma unroll
        for (int j = 0; j < 4; ++j) {
            float q = hhv + pp[p4 + j] - 2.0f * dd[j];
            q = q > 0.0f ? q : 0.0f;
            sim[node * 17 + p4 + j] = logf((q + 1.0f) / (q + 1e-4f));
        }
    }
    __syncthreads();

    if (t < 64) {
        int g = n0 + t;
        if (g < N) {
            float zacc = bf1l;
#pragma unroll
            for (int o = 0; o < 8; ++o) {
                float s = bf0l[o];
#pragma unroll
                for (int i2 = 0; i2 < 16; ++i2) s += sim[t * 17 + i2] * Wf0l[i2 * 8 + o];
                float gz = 0.5f * s * (1.0f + erff(s * 0.70710678118654752f));
                zacc += gz * Wf1l[o];
            }
            out[g] = 1.0f / (1.0f + expf(-zacc));
        }
    } else if (t < 128) {
        int g = n0 + (t - 64);
        if (g < N) out[N + g] = (float)y[g];
    }
}

// ---------------------------------------------------------------------------

extern "C" void kernel_launch(void* const* d_in, const int* in_sizes, int n_in,
                              void* d_out, int out_size, void* d_ws, size_t ws_size,
                              hipStream_t stream) {
    const float* x   = (const float*)d_in[0];
    const int*   ei  = (const int*)d_in[1];
    const int*   y   = (const int*)d_in[2];
    const float* W1  = (const float*)d_in[3];
    const float* b1  = (const float*)d_in[4];
    const float* W2  = (const float*)d_in[5];
    const float* b2  = (const float*)d_in[6];
    const float* W3  = (const float*)d_in[7];
    const float* b3  = (const float*)d_in[8];
    const float* pr  = (const float*)d_in[9];
    const float* Wf0 = (const float*)d_in[10];
    const float* bf0 = (const float*)d_in[11];
    const float* Wf1 = (const float*)d_in[12];
    const float* bf1 = (const float*)d_in[13];
    float* outp = (float*)d_out;

    const int N = in_sizes[2];       // 50000
    const int E = in_sizes[1] / 2;   // 800000
    const int NB = (N + BKT_NODES - 1) / BKT_NODES;   // 1563
    const int B = (E + EPB - 1) / EPB;                // 391 (<=512)

    char* w = (char*)d_ws;
    auto carve = [&](size_t bytes) {
        char* p = w;
        w += (bytes + 511) & ~(size_t)511;
        return p;
    };
    int*   glens   = (int*)carve((size_t)B * NB * 4);
    int*   gstart  = (int*)carve((size_t)B * NB * 4);
    int*   esort   = (int*)carve((size_t)B * EPB * 4);
    int*   row_beg = (int*)carve((size_t)N * 4);
    int*   row_end = (int*)carve((size_t)N * 4);
    float* dinv    = (float*)carve((size_t)N * 4);
    int*   csr     = (int*)carve((size_t)NB * LCAP * 4);
    __hip_bfloat16* Wp1 = (__hip_bfloat16*)carve(16384 * 2);
    __hip_bfloat16* Wp2 = (__hip_bfloat16*)carve(8192 * 2);
    __hip_bfloat16* Wp3 = (__hip_bfloat16*)carve(4096 * 2);
    __hip_bfloat16* bufT = (__hip_bfloat16*)carve((size_t)N * 128 * 2);
    __hip_bfloat16* bufH = (__hip_bfloat16*)carve((size_t)N * 128 * 2);

    size_t sort_lds = (size_t)(2 * NB + EPB) * 4;   // ~20.7 KB

    sort_local_kernel<<<B + PREPB, 256, sort_lds, stream>>>(ei, E, NB, B, glens, gstart, esort,
                                                            W1, W2, W3, Wp1, Wp2, Wp3);
    csr_build_kernel<<<NB, 256, 0, stream>>>(esort, glens, gstart, NB, B, N,
                                             row_beg, row_end, dinv, csr);

    // L1: x(f32,128) @ W1 -> bufT(bf16,128, dinv-prescaled); agg128 -> bufH
    mfma_gemm_kernel<128, 128, true><<<(N + 63) / 64, 256, 0, stream>>>(x, Wp1, dinv, bufT, N);
    agg128_kernel<<<(N + 3) / 4, 256, 0, stream>>>((const uint4*)bufT, b1, dinv, row_beg, row_end,
                                                   csr, (uint4*)bufH, N);
    // L2
    mfma_gemm_kernel<128, 64, false><<<(N + 63) / 64, 256, 0, stream>>>(bufH, Wp2, dinv, bufT, N);
    agg64_kernel<<<(N + 3) / 4, 256, 0, stream>>>((const uint4*)bufT, b2, dinv, row_beg, row_end,
                                                  csr, (uint4*)bufH, N);
    // L3
    mfma_gemm_kernel<64, 64, false><<<(N + 63) / 64, 256, 0, stream>>>(bufH, Wp3, dinv, bufT, N);
    agg64_kernel<<<(N + 3) / 4, 256, 0, stream>>>((const uint4*)bufT, b3, dinv, row_beg, row_end,
                                                  csr, (uint4*)bufH, N);
    // Head
    head_kernel<<<(N + 63) / 64, 256, 0, stream>>>((const unsigned*)bufH, pr, Wf0, bf0, Wf1, bf1,
                                                   y, outp, N);
}